// Round 12
// baseline (194.682 us; speedup 1.0000x reference)
//
#include <hip/hip_runtime.h>
#include <hip/hip_bf16.h>
#include <math.h>

typedef __attribute__((__ext_vector_type__(8))) short bf16x8;
typedef __attribute__((__ext_vector_type__(4))) float f32x4;
typedef __attribute__((__ext_vector_type__(16))) float f32x16;
typedef __attribute__((__ext_vector_type__(4))) unsigned int u32x4;

#define B_ 2
#define S_ 2048
#define D_ 1024
#define H_ 16
#define DK_ 64
#define M_ (B_*S_)
#define N3_ 3072
#define BIAS_LEN 4096
#define M0_ 24.0f
#define L2E_ 1.4426950408889634f
#define KSTRIDE 66   // padded LDS row stride (shorts): 33 dwords -> conflict-free

// hardware packed f32->bf16 (RNE), one instruction
__device__ __forceinline__ unsigned int cvtpk(float a, float b){
  unsigned int r;
  asm("v_cvt_pk_bf16_f32 %0, %1, %2" : "=v"(r) : "v"(a), "v"(b));
  return r;
}
__device__ __forceinline__ unsigned short f2bf(float f){
  unsigned int r;
  asm("v_cvt_pk_bf16_f32 %0, %1, %2" : "=v"(r) : "v"(f), "v"(f));
  return (unsigned short)r;
}
__device__ __forceinline__ float bf2f(unsigned short u){
  union{unsigned int i; float f;} v; v.i = ((unsigned int)u)<<16; return v.f;
}

__device__ __forceinline__ float fexp2(float x){
#if __has_builtin(__builtin_amdgcn_exp2f)
  return __builtin_amdgcn_exp2f(x);
#else
  return __expf(x * 0.6931471805599453f);
#endif
}

__device__ __forceinline__ f32x4 zero4(){
  f32x4 z; z[0]=0.f; z[1]=0.f; z[2]=0.f; z[3]=0.f; return z;
}

__device__ __forceinline__ f32x4 mfma16(bf16x8 a, bf16x8 b, f32x4 c){
  return __builtin_amdgcn_mfma_f32_16x16x32_bf16(a, b, c, 0, 0, 0);
}
__device__ __forceinline__ f32x16 mfma32(bf16x8 a, bf16x8 b, f32x16 c){
  return __builtin_amdgcn_mfma_f32_32x32x16_bf16(a, b, c, 0, 0, 0);
}

// async global->LDS, 16B per lane (linear LDS dest: base + lane*16)
__device__ __forceinline__ void gload16(const void* g, void* l){
  __builtin_amdgcn_global_load_lds(
      (const __attribute__((address_space(1))) void*)g,
      (__attribute__((address_space(3))) void*)l, 16, 0, 0);
}

// ---------------- weight transpose + cast ----------------
__global__ __launch_bounds__(256) void transpose_cast_kernel(
    const float* __restrict__ Wq, const float* __restrict__ Wk,
    const float* __restrict__ Wv, const float* __restrict__ Wo,
    unsigned short* __restrict__ Wcat_t, unsigned short* __restrict__ Wo_t)
{
  __shared__ float tile[64][65];
  const int k0 = blockIdx.x * 64;
  const int v0 = blockIdx.y * 64;
  const int sel = v0 >> 10;
  const float* W = (sel==0) ? Wq : (sel==1) ? Wk : (sel==2) ? Wv : Wo;
  const int nn0 = v0 & 1023;
  #pragma unroll
  for (int i=0;i<16;i++){
    int idx = i*256 + threadIdx.x;
    int r = idx >> 6, c = idx & 63;
    tile[r][c] = W[(size_t)(k0+r)*1024 + nn0 + c];
  }
  __syncthreads();
  #pragma unroll
  for (int i=0;i<16;i++){
    int idx = i*256 + threadIdx.x;
    int nr = idx >> 6, kc = idx & 63;
    unsigned short bv = f2bf(tile[kc][nr]);
    if (sel < 3) Wcat_t[(size_t)(v0+nr)*1024 + k0 + kc] = bv;
    else         Wo_t[(size_t)(v0-3072+nr)*1024 + k0 + kc] = bv;
  }
}

// ---------------- T5 bias table: tab[h][idx] = (bias - M0) * log2(e) ----------------
__global__ __launch_bounds__(256) void bias_tab_kernel(
    const float* __restrict__ rel_bias, float* __restrict__ biasTab)
{
  int t = blockIdx.x*256 + threadIdx.x;
  if (t >= H_*BIAS_LEN) return;
  int h = t / BIAS_LEN;
  int idx = t - h*BIAS_LEN;
  int rel = idx - (S_-1);
  int ret = (rel > 0) ? 16 : 0;
  int n = (rel < 0) ? -rel : rel;
  int bidx;
  if (n < 8) bidx = n;
  else {
    float vl = logf((float)n * 0.125f) / 2.7725887f * 8.0f; // log(16)
    int v = 8 + (int)vl;
    bidx = (v < 15) ? v : 15;
  }
  biasTab[t] = (rel_bias[(ret + bidx)*H_ + h] - M0_) * L2E_;
}

// ---------------- LayerNorm (fp32 in, bf16 out) ----------------
__global__ __launch_bounds__(256) void ln_kernel(
    const float* __restrict__ x, const float* __restrict__ g,
    const float* __restrict__ bta, unsigned short* __restrict__ out)
{
  const int row = blockIdx.x;
  const int tid = threadIdx.x;
  float4 v = ((const float4*)(x + (size_t)row*D_))[tid];
  float s  = v.x+v.y+v.z+v.w;
  float ss = v.x*v.x+v.y*v.y+v.z*v.z+v.w*v.w;
  #pragma unroll
  for (int off=1; off<64; off<<=1){ s += __shfl_xor(s,off,64); ss += __shfl_xor(ss,off,64); }
  __shared__ float rs[4], rss[4];
  const int wid = tid >> 6, lane = tid & 63;
  if (lane == 0){ rs[wid] = s; rss[wid] = ss; }
  __syncthreads();
  s  = rs[0]+rs[1]+rs[2]+rs[3];
  ss = rss[0]+rss[1]+rss[2]+rss[3];
  float mu  = s * (1.0f/1024.0f);
  float var = ss * (1.0f/1024.0f) - mu*mu;
  float rstd = rsqrtf(var + 1e-6f);
  float4 gg = ((const float4*)g)[tid];
  float4 bb = ((const float4*)bta)[tid];
  uint2 o;
  o.x = cvtpk((v.x-mu)*rstd*gg.x + bb.x, (v.y-mu)*rstd*gg.y + bb.y);
  o.y = cvtpk((v.z-mu)*rstd*gg.z + bb.z, (v.w-mu)*rstd*gg.w + bb.w);
  ((uint2*)(out + (size_t)row*D_))[tid] = o;
}

// ---------------- 128x128 bf16 MFMA GEMM: QKV projection ----------------
__global__ __launch_bounds__(256) void gemm_qkv_kernel(
    const unsigned short* __restrict__ A,
    const unsigned short* __restrict__ Bt,
    unsigned short* __restrict__ Qb,
    unsigned short* __restrict__ Kb,
    unsigned short* __restrict__ Vtb)
{
  __shared__ unsigned short As[128*64];
  __shared__ unsigned short Bs[128*64];
  const int tid = threadIdx.x;
  const int wid = tid >> 6, lane = tid & 63;
  const int lr = lane & 15, lg = lane >> 4;
  const int wm = (wid >> 1) * 64, wn = (wid & 1) * 64;

  const int nbx = gridDim.x;
  const int total = nbx * gridDim.y;
  const int flat = blockIdx.y * nbx + blockIdx.x;
  const int swz = (flat & 7) * (total >> 3) + (flat >> 3);
  const int m0 = (swz % nbx) * 128, n0 = (swz / nbx) * 128;

  f32x4 acc[4][4];
  #pragma unroll
  for (int i=0;i<4;i++)
    #pragma unroll
    for (int j=0;j<4;j++) acc[i][j] = zero4();

  for (int k0 = 0; k0 < D_; k0 += 64) {
    __syncthreads();
    #pragma unroll
    for (int i=0;i<4;i++){
      int c = i*256 + tid;
      int row = c >> 3, ch = c & 7;
      int chs = ch ^ (row & 7);
      gload16(A  + (size_t)(m0+row)*D_ + k0 + chs*8, As + c*8);
      gload16(Bt + (size_t)(n0+row)*D_ + k0 + chs*8, Bs + c*8);
    }
    __syncthreads();
    #pragma unroll
    for (int kk=0;kk<2;kk++){
      bf16x8 aF[4], bF[4];
      #pragma unroll
      for (int mi=0;mi<4;mi++){
        int row = wm + mi*16 + lr;
        aF[mi] = *(const bf16x8*)&As[row*64 + (((kk*4+lg) ^ (row & 7)) * 8)];
      }
      #pragma unroll
      for (int ni=0;ni<4;ni++){
        int row = wn + ni*16 + lr;
        bF[ni] = *(const bf16x8*)&Bs[row*64 + (((kk*4+lg) ^ (row & 7)) * 8)];
      }
      #pragma unroll
      for (int mi=0;mi<4;mi++)
        #pragma unroll
        for (int ni=0;ni<4;ni++)
          acc[mi][ni] = mfma16(aF[mi], bF[ni], acc[mi][ni]);
    }
  }

  const int seln = n0 >> 10;          // block-uniform
  if (seln == 2) {
    #pragma unroll
    for (int mi=0;mi<4;mi++)
      #pragma unroll
      for (int ni=0;ni<4;ni++){
        int m = m0 + wm + mi*16 + lg*4;
        int n = n0 + wn + ni*16 + lr;
        int nn = n & 1023, hh = nn >> 6, dk = nn & 63;
        int b = m >> 11, s = m & 2047;
        uint2 u;
        u.x = cvtpk(acc[mi][ni][0], acc[mi][ni][1]);
        u.y = cvtpk(acc[mi][ni][2], acc[mi][ni][3]);
        *(uint2*)(Vtb + (((size_t)(b*H_+hh))*DK_ + dk)*S_ + s) = u;
      }
  } else {
    unsigned short* __restrict__ dst = (seln == 0) ? Qb : Kb;
    #pragma unroll
    for (int mi=0;mi<4;mi++)
      #pragma unroll
      for (int ni=0;ni<4;ni++)
        #pragma unroll
        for (int r=0;r<4;r++){
          int m = m0 + wm + mi*16 + lg*4 + r;
          int n = n0 + wn + ni*16 + lr;
          int nn = n & 1023, hh = nn >> 6, dk = nn & 63;
          int b = m >> 11, s = m & 2047;
          dst[(((size_t)(b*H_+hh))*S_ + s)*DK_ + dk] = f2bf(acc[mi][ni][r]);
        }
  }
}

// softmax + PV for one 32-q group, one 32-key st-block.
// Exchange via __shfl_xor(.,32) + hi?: selects (R8-proven mapping).
#define SOFTMAX_PV(Svec, BG, UNIP, UNIN, VF00, VF01, VF10, VF11, ACC, LS)        \
{                                                                                \
  float p[16];                                                                   \
  if (UNIP) {                                                                    \
    _Pragma("unroll")                                                            \
    for (int r=0;r<16;r++) p[r] = fexp2(__builtin_fmaf(Svec[r], L2E_, cpos));    \
  } else if (UNIN) {                                                             \
    _Pragma("unroll")                                                            \
    for (int r=0;r<16;r++) p[r] = fexp2(__builtin_fmaf(Svec[r], L2E_, cneg));    \
  } else {                                                                       \
    _Pragma("unroll")                                                            \
    for (int r=0;r<16;r++){                                                      \
      int key = k0 + st*32 + (r&3) + 8*(r>>2) + 4*hi;                            \
      p[r] = fexp2(__builtin_fmaf(Svec[r], L2E_, BG[key]));                      \
    }                                                                            \
  }                                                                              \
  /* depth-4 tree sum, single add into LS */                                     \
  {                                                                              \
    float t0=p[0]+p[1], t1=p[2]+p[3], t2=p[4]+p[5], t3=p[6]+p[7];                \
    float t4=p[8]+p[9], t5=p[10]+p[11], t6=p[12]+p[13], t7=p[14]+p[15];          \
    LS += ((t0+t1)+(t2+t3)) + ((t4+t5)+(t6+t7));                                 \
  }                                                                              \
  unsigned int W00=cvtpk(p[0],p[1]),  W01=cvtpk(p[4],p[5]);                      \
  unsigned int W02=cvtpk(p[8],p[9]),  W03=cvtpk(p[12],p[13]);                    \
  unsigned int W10=cvtpk(p[2],p[3]),  W11=cvtpk(p[6],p[7]);                      \
  unsigned int W12=cvtpk(p[10],p[11]),W13=cvtpk(p[14],p[15]);                    \
  unsigned int X00=__shfl_xor(W00,32), X01=__shfl_xor(W01,32);                   \
  unsigned int X02=__shfl_xor(W02,32), X03=__shfl_xor(W03,32);                   \
  unsigned int X10=__shfl_xor(W10,32), X11=__shfl_xor(W11,32);                   \
  unsigned int X12=__shfl_xor(W12,32), X13=__shfl_xor(W13,32);                   \
  u32x4 pu0; u32x4 pu1;                                                          \
  pu0[0] = hi ? X01 : W00;  pu0[1] = hi ? X11 : W10;                             \
  pu0[2] = hi ? W01 : X00;  pu0[3] = hi ? W11 : X10;                             \
  pu1[0] = hi ? X03 : W02;  pu1[1] = hi ? X13 : W12;                             \
  pu1[2] = hi ? W03 : X02;  pu1[3] = hi ? W13 : X12;                             \
  bf16x8 pav0 = __builtin_bit_cast(bf16x8, pu0);                                 \
  bf16x8 pav1 = __builtin_bit_cast(bf16x8, pu1);                                 \
  ACC[0] = mfma32(pav0, VF00, ACC[0]);                                           \
  ACC[1] = mfma32(pav0, VF01, ACC[1]);                                           \
  ACC[0] = mfma32(pav1, VF10, ACC[0]);                                           \
  ACC[1] = mfma32(pav1, VF11, ACC[1]);                                           \
}

// ---------------- fused flash attention (64 q/wave, split-K over NS) ----------------
// grid: (8, 32, NS) blocks, XCD-swizzled. block 256 = 4 waves x 64 q-rows.
// Double-buffered K/V LDS: ONE barrier per tile (iter t reads buf[t&1],
// writes buf[(t+1)&1]; end-of-iter barrier closes all reads before rewrite).
template<int NS>
__global__ __launch_bounds__(256, 2) void attn_kernel(
    const unsigned short* __restrict__ Qb,
    const unsigned short* __restrict__ Kb,
    const unsigned short* __restrict__ Vtb,
    const float* __restrict__ biasTab,
    const float* __restrict__ rel_bias,
    unsigned short* __restrict__ Opart,
    float* __restrict__ Lpart)
{
  __shared__ unsigned short Ks[2][64*KSTRIDE];
  __shared__ unsigned short Vts[2][64*KSTRIDE];
  constexpr int NT = (S_/NS)/64;      // tiles per block
  constexpr int KSPAN = S_/NS;

  const int tid = threadIdx.x;
  const int wid = tid >> 6, lane = tid & 63;
  const int ql = lane & 31;
  const int hi = lane >> 5;

  // XCD swizzle: nblocks = 256*NS (multiple of 8); each XCD owns whole panels.
  const int flat = (blockIdx.z * 32 + blockIdx.y) * 8 + blockIdx.x;
  const int wf = (flat & 7) * (32 * NS) + (flat >> 3);
  const int qt = wf & 7;
  const int bh = (wf >> 3) & 31;
  const int kg = wf >> 8;

  const int h = bh & (H_-1);
  const int b = bh >> 4;
  const int kbase = kg * KSPAN;
  const int q0w = qt*256 + wid*64;   // wave's first q; groups at q0w and q0w+32

  const float cpos = (rel_bias[31*H_ + h] - M0_) * L2E_;
  const float cneg = (rel_bias[15*H_ + h] - M0_) * L2E_;
  const float* bGa = biasTab + (size_t)h*BIAS_LEN + 2047 - (q0w + ql);
  const float* bGb = bGa - 32;

  const unsigned short* Qpa = Qb + ((size_t)bh*S_ + q0w + ql)*DK_;
  bf16x8 qfa[4], qfb[4];
  #pragma unroll
  for (int c=0;c<4;c++){
    qfa[c] = *(const bf16x8*)(Qpa + 16*c + 8*hi);
    qfb[c] = *(const bf16x8*)(Qpa + 32*DK_ + 16*c + 8*hi);
  }

  const unsigned short* Ksrc = Kb  + (size_t)bh*S_*DK_;
  const unsigned short* Vsrc = Vtb + (size_t)bh*DK_*S_;
  const int c0 = tid, c1 = tid + 256;
  const int r0 = c0 >> 3, ch0 = c0 & 7;
  const int r1 = c1 >> 3, ch1 = c1 & 7;

  f32x16 acca[2], accb[2];
  #pragma unroll
  for (int i=0;i<16;i++){ acca[0][i]=0.f; acca[1][i]=0.f; accb[0][i]=0.f; accb[1][i]=0.f; }
  float lsa = 0.f, lsb = 0.f;

  // prologue: tile 0 -> regs -> buf0
  bf16x8 sk0 = *(const bf16x8*)(Ksrc + (size_t)(kbase + r0)*DK_ + ch0*8);
  bf16x8 sk1 = *(const bf16x8*)(Ksrc + (size_t)(kbase + r1)*DK_ + ch1*8);
  bf16x8 sv0 = *(const bf16x8*)(Vsrc + (size_t)r0*S_ + kbase + ch0*8);
  bf16x8 sv1 = *(const bf16x8*)(Vsrc + (size_t)r1*S_ + kbase + ch1*8);
  *(bf16x8*)&Ks [0][r0*KSTRIDE + ch0*8] = sk0;
  *(bf16x8*)&Ks [0][r1*KSTRIDE + ch1*8] = sk1;
  *(bf16x8*)&Vts[0][r0*KSTRIDE + ch0*8] = sv0;
  *(bf16x8*)&Vts[0][r1*KSTRIDE + ch1*8] = sv1;
  __syncthreads();

  for (int t = 0; t < NT; ++t) {
    const int k0 = kbase + t*64;
    const int cur = t & 1;
    if (t + 1 < NT) {
      int kn = k0 + 64;
      sk0 = *(const bf16x8*)(Ksrc + (size_t)(kn + r0)*DK_ + ch0*8);
      sk1 = *(const bf16x8*)(Ksrc + (size_t)(kn + r1)*DK_ + ch1*8);
      sv0 = *(const bf16x8*)(Vsrc + (size_t)r0*S_ + kn + ch0*8);
      sv1 = *(const bf16x8*)(Vsrc + (size_t)r1*S_ + kn + ch1*8);
    }
    const unsigned short* Ksb  = Ks[cur];
    const unsigned short* Vtsb = Vts[cur];

    const bool upa = (k0 >= q0w + 122),      una = (k0 <= q0w - 154);
    const bool upb = (k0 >= q0w + 32 + 122), unb = (k0 <= q0w + 32 - 154);

    #pragma unroll
    for (int st=0; st<2; ++st){
      const int arow = st*32 + ql;
      bf16x8 kf0 = *(const bf16x8*)&Ksb[arow*KSTRIDE + (0+hi)*8];
      bf16x8 kf1 = *(const bf16x8*)&Ksb[arow*KSTRIDE + (2+hi)*8];
      bf16x8 kf2 = *(const bf16x8*)&Ksb[arow*KSTRIDE + (4+hi)*8];
      bf16x8 kf3 = *(const bf16x8*)&Ksb[arow*KSTRIDE + (6+hi)*8];

      f32x16 sa, sb;
      #pragma unroll
      for (int i=0;i<16;i++){ sa[i]=0.f; sb[i]=0.f; }
      sa = mfma32(kf0, qfa[0], sa); sb = mfma32(kf0, qfb[0], sb);
      sa = mfma32(kf1, qfa[1], sa); sb = mfma32(kf1, qfb[1], sb);
      sa = mfma32(kf2, qfa[2], sa); sb = mfma32(kf2, qfb[2], sb);
      sa = mfma32(kf3, qfa[3], sa); sb = mfma32(kf3, qfb[3], sb);

      bf16x8 vf00 = *(const bf16x8*)&Vtsb[(ql     )*KSTRIDE + (4*st+  hi)*8];
      bf16x8 vf01 = *(const bf16x8*)&Vtsb[(ql + 32)*KSTRIDE + (4*st+  hi)*8];
      bf16x8 vf10 = *(const bf16x8*)&Vtsb[(ql     )*KSTRIDE + (4*st+2+hi)*8];
      bf16x8 vf11 = *(const bf16x8*)&Vtsb[(ql + 32)*KSTRIDE + (4*st+2+hi)*8];

      SOFTMAX_PV(sa, bGa, upa, una, vf00, vf01, vf10, vf11, acca, lsa);
      SOFTMAX_PV(sb, bGb, upb, unb, vf00, vf01, vf10, vf11, accb, lsb);
    }

    if (t + 1 < NT) {
      const int nxt = cur ^ 1;
      *(bf16x8*)&Ks [nxt][r0*KSTRIDE + ch0*8] = sk0;
      *(bf16x8*)&Ks [nxt][r1*KSTRIDE + ch1*8] = sk1;
      *(bf16x8*)&Vts[nxt][r0*KSTRIDE + ch0*8] = sv0;
      *(bf16x8*)&Vts[nxt][r1*KSTRIDE + ch1*8] = sv1;
    }
    __syncthreads();
  }

  // epilogue: store unnormalized partials for both q-groups
  float lta = lsa + __shfl_xor(lsa, 32);
  float ltb = lsb + __shfl_xor(lsb, 32);
  if (hi == 0) {
    Lpart[((size_t)kg*B_*H_ + bh)*S_ + q0w + ql]      = lta;
    Lpart[((size_t)kg*B_*H_ + bh)*S_ + q0w + 32 + ql] = ltb;
  }
  #pragma unroll
  for (int r=0;r<16;r++){
    const int qr = (r&3) + 8*(r>>2) + 4*hi;
    #pragma unroll
    for (int dt=0; dt<2; ++dt){
      const int d = ql + 32*dt;
      Opart[(size_t)kg*M_*D_ + ((size_t)(b*S_ + q0w + qr)*H_ + h)*DK_ + d]      = f2bf(acca[dt][r]);
      Opart[(size_t)kg*M_*D_ + ((size_t)(b*S_ + q0w + 32 + qr)*H_ + h)*DK_ + d] = f2bf(accb[dt][r]);
    }
  }
}

// ---------------- output GEMM with fused split-K combine + residual ----------------
template<int NS>
__global__ __launch_bounds__(256) void gemm_out_kernel(
    const unsigned short* __restrict__ Opart,   // [NS][M][D] bf16 unnormalized
    const float* __restrict__ Lpart,            // [NS][B*H][S]
    const unsigned short* __restrict__ Wo_t,    // [n][k] bf16
    const float* __restrict__ resid,
    float* __restrict__ outf)
{
  __shared__ unsigned short As[64*64];
  __shared__ unsigned short Bs[128*64];
  const int tid = threadIdx.x;
  const int wid = tid >> 6, lane = tid & 63;
  const int lr = lane & 15, lg = lane >> 4;
  const int wm = (wid & 1) * 32, wn = (wid >> 1) * 64;

  const int nbx = gridDim.x;                 // 64 m-tiles
  const int total = nbx * gridDim.y;         // 512
  const int flat = blockIdx.y * nbx + blockIdx.x;
  const int swz = (flat & 7) * (total >> 3) + (flat >> 3);
  const int m0 = (swz % nbx) * 64, n0 = (swz / nbx) * 128;

  f32x4 acc[2][4];
  #pragma unroll
  for (int i=0;i<2;i++)
    #pragma unroll
    for (int j=0;j<4;j++) acc[i][j] = zero4();

  for (int k0 = 0; k0 < D_; k0 += 64) {
    const int hh = k0 >> 6;                  // block-uniform head index
    __syncthreads();
    #pragma unroll
    for (int i=0;i<4;i++){
      int c = i*256 + tid;
      int row = c >> 3, ch = c & 7;
      int chs = ch ^ (row & 7);
      gload16(Wo_t + (size_t)(n0+row)*D_ + k0 + chs*8, Bs + c*8);
    }
    // A staging: combine NS partials, scale by 1/sum(l), cvt bf16, swizzled ds_write
    #pragma unroll
    for (int i=0;i<2;i++){
      int c = i*256 + tid;
      int row = c >> 3, ch = c & 7;
      int m = m0 + row;
      int bb = m >> 11, s = m & 2047;
      int bhh = bb*H_ + hh;
      float lsum = 0.f;
      #pragma unroll
      for (int s2=0;s2<NS;s2++) lsum += Lpart[((size_t)s2*B_*H_ + bhh)*S_ + s];
      float li = 1.0f / lsum;
      size_t addr = (size_t)m*D_ + k0 + ch*8;
      float va[8];
      #pragma unroll
      for (int j=0;j<8;j++) va[j] = 0.f;
      #pragma unroll
      for (int s2=0;s2<NS;s2++){
        bf16x8 p = *(const bf16x8*)(Opart + (size_t)s2*M_*D_ + addr);
        #pragma unroll
        for (int j=0;j<8;j++) va[j] += bf2f((unsigned short)p[j]);
      }
      u32x4 o;
      #pragma unroll
      for (int j=0;j<4;j++) o[j] = cvtpk(va[2*j]*li, va[2*j+1]*li);
      *(u32x4*)&As[row*64 + ((ch ^ (row & 7))*8)] = o;
    }
    __syncthreads();
    #pragma unroll
    for (int kk=0;kk<2;kk++){
      bf16x8 aF[2], bF[4];
      #pragma unroll
      for (int mi=0;mi<2;mi++){
        int row = wm + mi*16 + lr;
        aF[mi] = *(const bf16x8*)&As[row*64 + (((kk*4+lg) ^ (row & 7)) * 8)];
      }
      #pragma unroll
      for (int ni=0;ni<4;ni++){
        int row = wn + ni*16 + lr;
        bF[ni] = *(const bf16x8*)&Bs[row*64 + (((kk*4+lg) ^ (row & 7)) * 8)];
      }
      #pragma unroll
      for (int mi=0;mi<2;mi++)
        #pragma unroll
        for (int ni=0;ni<4;ni++)
          acc[mi][ni] = mfma16(aF[mi], bF[ni], acc[mi][ni]);
    }
  }

  #pragma unroll
  for (int mi=0;mi<2;mi++)
    #pragma unroll
    for (int ni=0;ni<4;ni++)
      #pragma unroll
      for (int r=0;r<4;r++){
        int m = m0 + wm + mi*16 + lg*4 + r;
        int n = n0 + wn + ni*16 + lr;
        outf[(size_t)m*D_ + n] = acc[mi][ni][r] + resid[(size_t)m*D_ + n];
      }
}

// ---------------- launcher ----------------
extern "C" void kernel_launch(void* const* d_in, const int* in_sizes, int n_in,
                              void* d_out, int out_size, void* d_ws, size_t ws_size,
                              hipStream_t stream) {
  const float* hidden   = (const float*)d_in[0];
  const float* ln_g     = (const float*)d_in[1];
  const float* ln_b     = (const float*)d_in[2];
  const float* Wq       = (const float*)d_in[3];
  const float* Wk       = (const float*)d_in[4];
  const float* Wv       = (const float*)d_in[5];
  const float* Wo       = (const float*)d_in[6];
  const float* rel_bias = (const float*)d_in[7];
  float* out = (float*)d_out;

  char* ws = (char*)d_ws;
  const size_t SZP = (size_t)M_*D_*2;          // one partial: 8,388,608
  const bool split4 = ws_size >= 62128128ULL;  // split-4 layout footprint

  size_t off_q, off_k, off_vt, off_bias, off_lp, off_wo;
  if (split4) {
    // Opart[0, 4*SZP=33,554,432); ln_out/Wcat_t alias Opart (dead before attn)
    off_q    = 33554432;
    off_k    = 41943040;
    off_vt   = 50331648;
    off_bias = 58720256;
    off_lp   = 58982400;   // 4*32*2048*4 = 1,048,576
    off_wo   = 60030976;   // +2,097,152 = 62,128,128
  } else {
    // proven split-2 layout
    off_q    = 16777216;
    off_k    = 25165824;
    off_vt   = 33554432;
    off_bias = 50331648;
    off_lp   = 50593792;
    off_wo   = 51118080;
  }

  unsigned short* ln_out  = (unsigned short*)(ws + 0);
  unsigned short* Wcat_t  = (unsigned short*)(ws + SZP);
  unsigned short* Wo_t    = (unsigned short*)(ws + off_wo);
  unsigned short* Qb      = (unsigned short*)(ws + off_q);
  unsigned short* Kb      = (unsigned short*)(ws + off_k);
  unsigned short* Vtb     = (unsigned short*)(ws + off_vt);
  float*          biasTab = (float*)(ws + off_bias);
  float*          Lpart   = (float*)(ws + off_lp);
  unsigned short* Opart   = (unsigned short*)(ws + 0);

  transpose_cast_kernel<<<dim3(16,64), 256, 0, stream>>>(Wq, Wk, Wv, Wo, Wcat_t, Wo_t);
  bias_tab_kernel<<<(H_*BIAS_LEN + 255)/256, 256, 0, stream>>>(rel_bias, biasTab);
  ln_kernel<<<M_, 256, 0, stream>>>(hidden, ln_g, ln_b, ln_out);
  gemm_qkv_kernel<<<dim3(M_/128, N3_/128), 256, 0, stream>>>(
      ln_out, Wcat_t, Qb, Kb, Vtb);
  if (split4) {
    attn_kernel<4><<<dim3(8, 32, 4), 256, 0, stream>>>(
        Qb, Kb, Vtb, biasTab, rel_bias, Opart, Lpart);
    gemm_out_kernel<4><<<dim3(M_/64, D_/128), 256, 0, stream>>>(
        Opart, Lpart, Wo_t, hidden, out);
  } else {
    attn_kernel<2><<<dim3(8, 32, 2), 256, 0, stream>>>(
        Qb, Kb, Vtb, biasTab, rel_bias, Opart, Lpart);
    gemm_out_kernel<2><<<dim3(M_/64, D_/128), 256, 0, stream>>>(
        Opart, Lpart, Wo_t, hidden, out);
  }
}